// Round 8
// baseline (924.988 us; speedup 1.0000x reference)
//
#include <hip/hip_runtime.h>

// Problem constants (B=32, S=512, C=256, H=8, NC=4, KW=7)
#define BB 32
#define SS 512
#define CC 256
#define NH 8
#define NCV 4
#define SSS_ (SS * SS)          // 262144

using s8v   = __attribute__((ext_vector_type(8))) short;   // 8 bf16 raw (4 VGPR)
using f32x4 = __attribute__((ext_vector_type(4))) float;

__device__ __forceinline__ unsigned short f2bf(float f) {
    union { float f; unsigned int u; } v; v.f = f;
    unsigned int r = (v.u + 0x7fffu + ((v.u >> 16) & 1u)) >> 16;   // RNE
    return (unsigned short)r;
}
__device__ __forceinline__ float bf2f(unsigned short u) {
    union { unsigned int u; float f; } v; v.u = ((unsigned int)u) << 16;
    return v.f;
}

// Direct global->LDS DMA, 16 B per lane. LDS dest must be wave-uniform base
// (HW writes base + lane*16); global src is per-lane. [m97/m151 pattern]
__device__ __forceinline__ void gl16(const void* g, void* l)
{
    __builtin_amdgcn_global_load_lds(
        (__attribute__((address_space(1))) void*)g,
        (__attribute__((address_space(3))) void*)l,
        16, 0, 0);
}

// ---------------------------------------------------------------------------
// MFMA GEMM (TN): C[m][n] = sum_k A[m][k]*B[n][k].  A row-major MxK bf16,
// B n-major NxK bf16.  128x128 tile, BK=32, 4 waves x (64x64).
// Staging via global_load_lds (m97 structure: stage -> barrier -> MFMA -> barrier).
// Generalized z-offsets: zlo = bz & zmask, zhi = bz >> zshift;
//   off_X = zhi*sX2 + zlo*sX1.
// flags: 1=OUT_BF16, 2=RELU, 4=ACCUM(f32 C+=)
// ---------------------------------------------------------------------------
#define F_OUT16 1
#define F_RELU  2
#define F_ACCUM 4

__global__ __launch_bounds__(256)
void gemm_mfma(const unsigned short* __restrict__ A, int lda, long long sA1, long long sA2,
               const unsigned short* __restrict__ B, int ldb, long long sB1, long long sB2,
               void* __restrict__ Cp, int ldc, long long sC1, long long sC2,
               int K, int zshift, int zmask,
               const float* __restrict__ bias,
               const float* __restrict__ resid,
               float alpha, int flags)
{
    __shared__ unsigned short As[128][32];
    __shared__ unsigned short Bs[128][32];
    const int bz = blockIdx.z;
    const long long zlo = bz & zmask, zhi = bz >> zshift;
    A += zhi * sA2 + zlo * sA1;
    B += zhi * sB2 + zlo * sB1;
    const long long coff = zhi * sC2 + zlo * sC1;
    float*          Cf  = (float*)Cp + coff;
    unsigned short* C16 = (unsigned short*)Cp + coff;
    const float*    Rp  = resid ? resid + coff : nullptr;

    const int m0 = blockIdx.x * 128, n0 = blockIdx.y * 128;
    const int t = threadIdx.x;
    const int w = t >> 6, lane = t & 63;
    const int wr = (w >> 1) * 64, wc = (w & 1) * 64;
    const int lr = lane & 15, lg = lane >> 4;

    // wave-uniform LDS bases: wave w stages rows [16w,16w+16) of each half
    unsigned short* ldsA0 = &As[0][0]  + w * 512;
    unsigned short* ldsA1 = &As[64][0] + w * 512;
    unsigned short* ldsB0 = &Bs[0][0]  + w * 512;
    unsigned short* ldsB1 = &Bs[64][0] + w * 512;

    // per-lane global sources (lane l -> row 16w + l/4, 16B slot l%4)
    const int srow = t >> 2, sslot = t & 3;
    const unsigned short* Ag0 = A + (size_t)(m0 + srow) * lda + sslot * 8;
    const unsigned short* Ag1 = Ag0 + (size_t)64 * lda;
    const unsigned short* Bg0 = B + (size_t)(n0 + srow) * ldb + sslot * 8;
    const unsigned short* Bg1 = Bg0 + (size_t)64 * ldb;

    f32x4 acc[4][4] = {};
    const int nt = K / 32;

    for (int tk = 0; tk < nt; ++tk) {
        const int ko = tk * 32;
        gl16(Ag0 + ko, ldsA0);
        gl16(Ag1 + ko, ldsA1);
        gl16(Bg0 + ko, ldsB0);
        gl16(Bg1 + ko, ldsB1);
        __syncthreads();                       // compiler drains vmcnt before barrier
        s8v af[4], bf[4];
        #pragma unroll
        for (int mi = 0; mi < 4; ++mi)
            af[mi] = *(const s8v*)&As[wr + mi * 16 + lr][lg * 8];
        #pragma unroll
        for (int ni = 0; ni < 4; ++ni)
            bf[ni] = *(const s8v*)&Bs[wc + ni * 16 + lr][lg * 8];
        #pragma unroll
        for (int mi = 0; mi < 4; ++mi)
            #pragma unroll
            for (int ni = 0; ni < 4; ++ni)
                acc[mi][ni] = __builtin_amdgcn_mfma_f32_16x16x32_bf16(
                    af[mi], bf[ni], acc[mi][ni], 0, 0, 0);
        __syncthreads();                       // compute done before next overwrite
    }

    float bv[4] = {0.f, 0.f, 0.f, 0.f};
    if (bias) {
        #pragma unroll
        for (int ni = 0; ni < 4; ++ni) bv[ni] = bias[n0 + wc + ni * 16 + lr];
    }
    #pragma unroll
    for (int mi = 0; mi < 4; ++mi) {
        #pragma unroll
        for (int j = 0; j < 4; ++j) {
            size_t ro = (size_t)(m0 + wr + mi * 16 + lg * 4 + j) * ldc;
            #pragma unroll
            for (int ni = 0; ni < 4; ++ni) {
                int gc = n0 + wc + ni * 16 + lr;
                float v = acc[mi][ni][j] * alpha + bv[ni];
                if (flags & F_RELU) v = fmaxf(v, 0.f);
                if (Rp) v += Rp[ro + gc];
                if (flags & F_ACCUM) v += Cf[ro + gc];
                if (flags & F_OUT16) C16[ro + gc] = f2bf(v);
                else                 Cf[ro + gc] = v;
            }
        }
    }
}

// ---------------------------------------------------------------------------
// Conv1d(k=7, same pad) as gather-A MFMA GEMM, global_load_lds staging.
// OOB rows redirect their per-lane SOURCE to a zeroed 128B scratch (zbuf).
// ---------------------------------------------------------------------------
__global__ __launch_bounds__(256)
void conv_mfma(const unsigned short* __restrict__ h16,
               const unsigned short* __restrict__ Bw,
               const float* __restrict__ bias,
               const float* __restrict__ resid,
               float* __restrict__ C,
               const unsigned short* __restrict__ zbuf)
{
    __shared__ unsigned short As[128][32];
    __shared__ unsigned short Bs[128][32];
    const int m0 = blockIdx.x * 128, n0 = blockIdx.y * 128;
    const int t = threadIdx.x;
    const int w = t >> 6, lane = t & 63;
    const int wr = (w >> 1) * 64, wc = (w & 1) * 64;
    const int lr = lane & 15, lg = lane >> 4;

    unsigned short* ldsA0 = &As[0][0]  + w * 512;
    unsigned short* ldsA1 = &As[64][0] + w * 512;
    unsigned short* ldsB0 = &Bs[0][0]  + w * 512;
    unsigned short* ldsB1 = &Bs[64][0] + w * 512;

    const int srow = t >> 2, sslot = t & 3;
    const int gm0 = m0 + srow;
    const int b0_ = gm0 >> 9, s0_ = gm0 & (SS - 1);
    const int gm1 = gm0 + 64;
    const int b1_ = gm1 >> 9, s1_ = gm1 & (SS - 1);
    const unsigned short* Bg0 = Bw + (size_t)(n0 + srow) * (7 * CC) + sslot * 8;
    const unsigned short* Bg1 = Bg0 + (size_t)64 * (7 * CC);

    f32x4 acc[4][4] = {};
    const int nt = (7 * CC) / 32;       // 56

    for (int tk = 0; tk < nt; ++tk) {
        const int kg = tk * 32 + sslot * 8;
        const int kw = kg >> 8, ci = kg & (CC - 1);
        const int ss0 = s0_ + kw - 3, ss1 = s1_ + kw - 3;
        const unsigned short* a0 = ((unsigned)ss0 < (unsigned)SS)
            ? &h16[((size_t)(b0_ * SS + ss0)) * CC + ci] : zbuf;
        const unsigned short* a1 = ((unsigned)ss1 < (unsigned)SS)
            ? &h16[((size_t)(b1_ * SS + ss1)) * CC + ci] : zbuf;
        gl16(a0, ldsA0);
        gl16(a1, ldsA1);
        gl16(Bg0 + tk * 32, ldsB0);
        gl16(Bg1 + tk * 32, ldsB1);
        __syncthreads();
        s8v af[4], bf[4];
        #pragma unroll
        for (int mi = 0; mi < 4; ++mi)
            af[mi] = *(const s8v*)&As[wr + mi * 16 + lr][lg * 8];
        #pragma unroll
        for (int ni = 0; ni < 4; ++ni)
            bf[ni] = *(const s8v*)&Bs[wc + ni * 16 + lr][lg * 8];
        #pragma unroll
        for (int mi = 0; mi < 4; ++mi)
            #pragma unroll
            for (int ni = 0; ni < 4; ++ni)
                acc[mi][ni] = __builtin_amdgcn_mfma_f32_16x16x32_bf16(
                    af[mi], bf[ni], acc[mi][ni], 0, 0, 0);
        __syncthreads();
    }

    float bv[4];
    #pragma unroll
    for (int ni = 0; ni < 4; ++ni) bv[ni] = bias[n0 + wc + ni * 16 + lr];
    #pragma unroll
    for (int mi = 0; mi < 4; ++mi) {
        #pragma unroll
        for (int j = 0; j < 4; ++j) {
            size_t ro = (size_t)(m0 + wr + mi * 16 + lg * 4 + j) * CC;
            #pragma unroll
            for (int ni = 0; ni < 4; ++ni) {
                int gc = n0 + wc + ni * 16 + lr;
                C[ro + gc] = acc[mi][ni][j] + bv[ni] + resid[ro + gc];
            }
        }
    }
}

// ---------------------------------------------------------------------------
__global__ void zero_kernel(unsigned short* p) { p[threadIdx.x] = 0; }

// ---------------------------------------------------------------------------
// Cast+transpose: src f32 (R x Cn) -> dst bf16 (Cn x R), batched over z.
// ---------------------------------------------------------------------------
__global__ __launch_bounds__(256)
void ct_kernel(const float* __restrict__ src, unsigned short* __restrict__ dst,
               int R, int Cn)
{
    __shared__ unsigned short tile[32][36];
    const size_t zoff = (size_t)blockIdx.z * R * Cn;
    src += zoff;  dst += zoff;
    const int r0 = blockIdx.x * 32, c0 = blockIdx.y * 32;
    const int t = threadIdx.x;
    const int r = t >> 3, c4 = (t & 7) * 4;
    float4 f = *(const float4*)&src[(size_t)(r0 + r) * Cn + c0 + c4];
    tile[r][c4 + 0] = f2bf(f.x);
    tile[r][c4 + 1] = f2bf(f.y);
    tile[r][c4 + 2] = f2bf(f.z);
    tile[r][c4 + 3] = f2bf(f.w);
    __syncthreads();
    ushort4 o;
    o.x = tile[c4 + 0][r];
    o.y = tile[c4 + 1][r];
    o.z = tile[c4 + 2][r];
    o.w = tile[c4 + 3][r];
    *(ushort4*)&dst[(size_t)(c0 + r) * R + r0 + c4] = o;
}

// ---------------------------------------------------------------------------
// Plain cast f32 -> bf16 for 3 equal-size weight arrays (wq, wk, wv).
// ---------------------------------------------------------------------------
__global__ __launch_bounds__(256)
void cast3_kernel(const float* __restrict__ a0, const float* __restrict__ a1,
                  const float* __restrict__ a2,
                  unsigned short* __restrict__ o0, unsigned short* __restrict__ o1,
                  unsigned short* __restrict__ o2)
{
    const float* s = (blockIdx.y == 0) ? a0 : (blockIdx.y == 1) ? a1 : a2;
    unsigned short* d = (blockIdx.y == 0) ? o0 : (blockIdx.y == 1) ? o1 : o2;
    int i4 = (blockIdx.x * 256 + threadIdx.x) * 4;
    float4 f = *(const float4*)&s[i4];
    ushort4 o;
    o.x = f2bf(f.x); o.y = f2bf(f.y); o.z = f2bf(f.z); o.w = f2bf(f.w);
    *(ushort4*)&d[i4] = o;
}

// ---------------------------------------------------------------------------
// out = x + position_encoding(s, c)   (f32)
// ---------------------------------------------------------------------------
__global__ __launch_bounds__(256)
void pe_add_kernel(const float* __restrict__ x, float* __restrict__ out, int n)
{
    int idx = blockIdx.x * 256 + threadIdx.x;
    if (idx >= n) return;
    int c = idx & (CC - 1);
    int s = (idx >> 8) & (SS - 1);
    int i = c >> 1;
    float e = (2.0f * (float)i / (float)CC) * 13.28771237954945f;  // log2(10000)
    float freq = exp2f(e);
    float ang = (float)s / freq;
    float pe = (c & 1) ? cosf(ang) : sinf(ang);
    out[idx] = x[idx] + pe;
}

// ---------------------------------------------------------------------------
// LayerNorm f32 in -> bf16 out. One wave per row (C=256), 4 floats/lane.
// ---------------------------------------------------------------------------
__global__ __launch_bounds__(256)
void ln16_kernel(const float* __restrict__ x, const float* __restrict__ g,
                 const float* __restrict__ b, unsigned short* __restrict__ y)
{
    int wave = threadIdx.x >> 6, lane = threadIdx.x & 63;
    size_t row = (size_t)blockIdx.x * 4 + wave;
    const float* xr = x + row * CC;
    float4 v = *(const float4*)&xr[lane * 4];

    float s = v.x + v.y + v.z + v.w;
    #pragma unroll
    for (int off = 32; off > 0; off >>= 1) s += __shfl_xor(s, off, 64);
    float m = s * (1.0f / CC);

    float4 d = make_float4(v.x - m, v.y - m, v.z - m, v.w - m);
    float sq = d.x * d.x + d.y * d.y + d.z * d.z + d.w * d.w;
    #pragma unroll
    for (int off = 32; off > 0; off >>= 1) sq += __shfl_xor(sq, off, 64);
    float rs = rsqrtf(sq * (1.0f / CC) + 1e-5f);

    float4 gg = *(const float4*)&g[lane * 4];
    float4 bv = *(const float4*)&b[lane * 4];
    ushort4 o;
    o.x = f2bf(d.x * rs * gg.x + bv.x);
    o.y = f2bf(d.y * rs * gg.y + bv.y);
    o.z = f2bf(d.z * rs * gg.z + bv.z);
    o.w = f2bf(d.w * rs * gg.w + bv.w);
    *(ushort4*)&y[row * CC + lane * 4] = o;
}

// ---------------------------------------------------------------------------
// Softmax over the BATCH axis, 2 heads per launch, bf16 in-place.
// 2 t-columns per thread (uint loads): 256B/wave per b-slice.
// ---------------------------------------------------------------------------
__global__ __launch_bounds__(256)
void softmax2_kernel(unsigned short* __restrict__ sc)
{
    int idx = blockIdx.x * 256 + threadIdx.x;            // pair index over 2*SSS/2
    int g2 = idx >> 17;                                  // SSS/2 = 2^17
    int st = (idx & 131071) * 2;
    unsigned short* p = sc + (size_t)g2 * (32u * SSS_) + st;
    float v0[BB], v1[BB];
    float m0 = -3.4e38f, m1 = -3.4e38f;
    #pragma unroll
    for (int b = 0; b < BB; ++b) {
        unsigned int u = *(const unsigned int*)&p[(size_t)b * SSS_];
        v0[b] = bf2f((unsigned short)(u & 0xffffu));
        v1[b] = bf2f((unsigned short)(u >> 16));
        m0 = fmaxf(m0, v0[b]);
        m1 = fmaxf(m1, v1[b]);
    }
    float s0 = 0.f, s1 = 0.f;
    #pragma unroll
    for (int b = 0; b < BB; ++b) {
        v0[b] = __expf(v0[b] - m0);  s0 += v0[b];
        v1[b] = __expf(v1[b] - m1);  s1 += v1[b];
    }
    float i0 = 1.0f / s0, i1 = 1.0f / s1;
    #pragma unroll
    for (int b = 0; b < BB; ++b) {
        unsigned int u = (unsigned int)f2bf(v0[b] * i0)
                       | ((unsigned int)f2bf(v1[b] * i1) << 16);
        *(unsigned int*)&p[(size_t)b * SSS_] = u;
    }
}

// ---------------------------------------------------------------------------
extern "C" void kernel_launch(void* const* d_in, const int* in_sizes, int n_in,
                              void* d_out, int out_size, void* d_ws, size_t ws_size,
                              hipStream_t stream)
{
    const float* x      = (const float*)d_in[0];
    const float* conv_w = (const float*)d_in[1];   // (NC, KW*C, C)
    const float* conv_b = (const float*)d_in[2];   // (NC, C)
    const float* ln_g   = (const float*)d_in[3];
    const float* ln_b   = (const float*)d_in[4];
    const float* wq     = (const float*)d_in[5];   // (H, C, C)
    const float* wk     = (const float*)d_in[6];
    const float* wv     = (const float*)d_in[7];
    const float* w_proj = (const float*)d_in[8];   // (H*C, C)
    const float* ff_w   = (const float*)d_in[9];
    const float* ff_b   = (const float*)d_in[10];
    const float* ff2_w  = (const float*)d_in[11];
    const float* ff2_b  = (const float*)d_in[12];
    float* out = (float*)d_out;

    // -------- workspace layout (peak 144 MiB, proven available) ------------
    char* W = (char*)d_ws;
    unsigned short* wq16 = (unsigned short*)(W + (0u  << 20));   // transient
    unsigned short* wk16 = (unsigned short*)(W + (1u  << 20));
    unsigned short* wv16 = (unsigned short*)(W + (2u  << 20));
    unsigned short* wpT  = (unsigned short*)(W + (3u  << 20));
    float*          bufA = (float*)(W + (0u  << 20));            // 16 MiB
    unsigned short* sc16 = (unsigned short*)(W + (0u  << 20));   // 32 MiB (after bufA dies)
    float*          bufC = (float*)(W + (32u << 20));            // 16 MiB
    unsigned short* h16  = (unsigned short*)(W + (48u << 20));   //  8 MiB
    unsigned short* qm16 = (unsigned short*)(W + (56u << 20));   // 64 MiB (H,B,S,C)
    unsigned short* ff16 = (unsigned short*)(W + (56u << 20));   //  8 MiB (reuse post-attn)
    unsigned short* zT16 = (unsigned short*)(W + (120u << 20));  // 16 MiB (2,B,C,S)
    unsigned short* convT = (unsigned short*)(W + (136u << 20)); // 3.5 MiB [136,139.5)
    unsigned short* zbuf  = (unsigned short*)(W + (139u << 20) + (512u << 10)); // 128 B zeros
    unsigned short* ffT   = (unsigned short*)(W + (140u << 20)); // 128 KiB
    unsigned short* ff2T  = (unsigned short*)(W + (141u << 20)); // 128 KiB
    unsigned short* Mh16  = (unsigned short*)(W + (142u << 20)); // 1 MiB (H,C,C)
    unsigned short* WfT16 = (unsigned short*)(W + (143u << 20)); // 1 MiB (H,C,C)

    const int M = BB * SS;                       // 16384
    const long long BSC = (long long)SS * CC;    // 131072
    const long long HBSC = (long long)BB * BSC;  // 4194304
    const long long CCC = (long long)CC * CC;    // 65536

    dim3 blk(256);

    // 0) weight precompute ---------------------------------------------------
    zero_kernel<<<1, 64, 0, stream>>>(zbuf);
    cast3_kernel<<<dim3(512, 3), blk, 0, stream>>>(wq, wk, wv, wq16, wk16, wv16);
    ct_kernel<<<dim3((7 * CC) / 32, CC / 32, NCV), blk, 0, stream>>>(conv_w, convT, 7 * CC, CC);
    ct_kernel<<<dim3((NH * CC) / 32, CC / 32, 1), blk, 0, stream>>>(w_proj, wpT, NH * CC, CC);
    ct_kernel<<<dim3(CC / 32, CC / 32, 1), blk, 0, stream>>>(ff_w, ffT, CC, CC);
    ct_kernel<<<dim3(CC / 32, CC / 32, 1), blk, 0, stream>>>(ff2_w, ff2T, CC, CC);
    // Mh[h][d][d'] = sum_e Wq[h][d][e] Wk[h][d'][e] / 16
    gemm_mfma<<<dim3(2, 2, NH), blk, 0, stream>>>(
        wq16, CC, 0, CCC, wk16, CC, 0, CCC, Mh16, CC, 0, CCC,
        CC, 0, 0, nullptr, nullptr, 0.0625f, F_OUT16);
    // WfT[h][e'][d] = sum_e wp[h*256+e][e'] Wv[h][d][e]
    gemm_mfma<<<dim3(2, 2, NH), blk, 0, stream>>>(
        wpT, NH * CC, 0, CC, wv16, CC, 0, CCC, WfT16, CC, 0, CCC,
        CC, 0, 0, nullptr, nullptr, 1.0f, F_OUT16);

    // 1) positional encoding -------------------------------------------------
    const int T = M * CC;
    pe_add_kernel<<<T / 256, blk, 0, stream>>>(x, bufA, T);

    // 2) conv stack ----------------------------------------------------------
    float* cur = bufA;
    float* alt = bufC;
    for (int k = 0; k < NCV; ++k) {
        ln16_kernel<<<M / 4, blk, 0, stream>>>(cur, ln_g, ln_b, h16);
        conv_mfma<<<dim3(M / 128, CC / 128), blk, 0, stream>>>(
            h16, convT + (size_t)k * (7 * CC) * CC, conv_b + k * CC, cur, alt, zbuf);
        float* tmp = cur; cur = alt; alt = tmp;
    }
    // result in bufA

    // 3) attention -----------------------------------------------------------
    ln16_kernel<<<M / 4, blk, 0, stream>>>(bufA, ln_g, ln_b, h16);
    hipMemcpyAsync(bufC, bufA, (size_t)T * sizeof(float),
                   hipMemcpyDeviceToDevice, stream);   // residual seed; bufA dead

    // qm[h][b,t,d] = sum_d' h[b,t,d'] Mh[h][d][d']
    gemm_mfma<<<dim3(M / 128, CC / 128, NH), blk, 0, stream>>>(
        h16, CC, 0, 0, Mh16, CC, 0, CCC, qm16, CC, 0, HBSC,
        CC, 0, 0, nullptr, nullptr, 1.0f, F_OUT16);

    for (int g = 0; g < NH / 2; ++g) {           // 2 heads per group
        const long long scH = 32LL * SSS_;
        const long long zTH = 32LL * BSC;
        // scores[g2][b][s][t] = sum_d h[b,s,d] qm[2g+g2][b,t,d]
        gemm_mfma<<<dim3(SS / 128, SS / 128, 64), blk, 0, stream>>>(
            h16, CC, BSC, 0,
            qm16 + (size_t)(2 * g) * HBSC, CC, BSC, HBSC,
            sc16, SS, SSS_, scH,
            CC, 5, 31, nullptr, nullptr, 1.0f, F_OUT16);
        softmax2_kernel<<<(2 * SSS_ / 2) / 256, blk, 0, stream>>>(sc16);
        // zT[g2][b][c][s] = sum_d WfT[2g+g2][c][d] h[b,s,d]
        gemm_mfma<<<dim3(CC / 128, SS / 128, 64), blk, 0, stream>>>(
            WfT16 + (size_t)(2 * g) * CCC, CC, 0, CCC,
            h16, CC, BSC, 0,
            zT16, SS, BSC, zTH,
            CC, 5, 31, nullptr, nullptr, 1.0f, F_OUT16);
        // bufC[b,s,c] += sum_t attn[g2][b,s,t] * zT[g2][b][c][t]
        for (int g2 = 0; g2 < 2; ++g2) {
            gemm_mfma<<<dim3(SS / 128, CC / 128, BB), blk, 0, stream>>>(
                sc16 + (size_t)g2 * scH, SS, 0, SSS_,
                zT16 + (size_t)g2 * zTH, SS, 0, BSC,
                bufC, CC, 0, BSC,
                SS, 0, 0, nullptr, nullptr, 1.0f, F_ACCUM);
        }
    }

    // 4) feed-forward (residual = bufC) --------------------------------------
    ln16_kernel<<<M / 4, blk, 0, stream>>>(bufC, ln_g, ln_b, h16);
    gemm_mfma<<<dim3(M / 128, CC / 128, 1), blk, 0, stream>>>(
        h16, CC, 0, 0, ffT, CC, 0, 0, ff16, CC, 0, 0,
        CC, 0, 0, ff_b, nullptr, 1.0f, F_OUT16 | F_RELU);
    gemm_mfma<<<dim3(M / 128, CC / 128, 1), blk, 0, stream>>>(
        ff16, CC, 0, 0, ff2T, CC, 0, 0, out, CC, 0, 0,
        CC, 0, 0, ff2_b, bufC, 1.0f, 0);
}